// Round 14
// baseline (66.533 us; speedup 1.0000x reference)
//
#include <hip/hip_runtime.h>

#define NROWS 8192
#define DIM 128
#define NT 64      // 128x128 tiles per side
#define NBLK 512   // pairwise blocks; block c owns 4(+1) consecutive tiles

typedef _Float16 f16x8 __attribute__((ext_vector_type(8)));
typedef _Float16 f16x2 __attribute__((ext_vector_type(2)));
typedef float f32x16 __attribute__((ext_vector_type(16)));

#define L2E 1.4426950408889634f  // log2(e)

#define AS1(p) ((const __attribute__((address_space(1))) void*)(p))
#define AS3(p) ((__attribute__((address_space(3))) void*)(p))

// ---------------------------------------------------------------------------
// Kernel 1: per-row L2 normalize (fp32, as reference). Unchanged (verified).
// ---------------------------------------------------------------------------
__global__ __launch_bounds__(1024) void fmicl_normalize(
    const float* __restrict__ z1, const float* __restrict__ z2,
    _Float16* __restrict__ zh, float* __restrict__ sposB) {
  const int wid = threadIdx.x >> 6;
  const int lane = threadIdx.x & 63;
  const int row = blockIdx.x * 16 + wid;
  const float2 a = ((const float2*)(z1 + (size_t)row * DIM))[lane];
  const float2 b = ((const float2*)(z2 + (size_t)row * DIM))[lane];
  float s1 = a.x * a.x + a.y * a.y;
  float s2 = b.x * b.x + b.y * b.y;
#pragma unroll
  for (int off = 32; off; off >>= 1) {
    s1 += __shfl_xor(s1, off);
    s2 += __shfl_xor(s2, off);
  }
  const float inv1 = 1.0f / fmaxf(sqrtf(s1), 1e-12f);
  const float inv2 = 1.0f / fmaxf(sqrtf(s2), 1e-12f);
  const float n1x = a.x * inv1, n1y = a.y * inv1;
  const float n2x = b.x * inv2, n2y = b.y * inv2;
  const float dx = n1x - n2x, dy = n1y - n2y;
  float dp = dx * dx + dy * dy;
#pragma unroll
  for (int off = 32; off; off >>= 1) dp += __shfl_xor(dp, off);
  f16x2 h;
  h.x = (_Float16)n1x;
  h.y = (_Float16)n1y;
  *(f16x2*)(zh + (size_t)row * DIM + 2 * lane) = h;
  __shared__ float sposL[16];
  if (lane == 0)
    sposL[wid] = logf(expf(-0.5f * dp) + 1e-8f) + 1.0f;  // f'(g_pos)
  __syncthreads();
  if (threadIdx.x == 0) {
    float s = 0.0f;
#pragma unroll
    for (int k = 0; k < 16; ++k) s += sposL[k];
    sposB[blockIdx.x] = s;
  }
}

// ---------------------------------------------------------------------------
// Stage one 128-row B panel (32 KiB) into LDS via global_load_lds width=16.
// LDS dest linear; global source pre-swizzled (granule col ^= row&15);
// read side applies the same XOR (involution; rounds 3-12 verified,
// 0 bank conflicts). 4 VMEM instructions per wave.
// ---------------------------------------------------------------------------
__device__ __forceinline__ void stageB(const _Float16* __restrict__ zh,
                                       _Float16* buf, int ct, int wid,
                                       int lane) {
  const _Float16* base = zh + ((size_t)ct << 7) * DIM;
#pragma unroll
  for (int it = 0; it < 4; ++it) {
    const int P = it * 8 + wid;          // wave-uniform 4-row group 0..31
    const int R = P * 4 + (lane >> 4);   // row 0..127
    const int cs = (lane & 15) ^ (R & 15);
    __builtin_amdgcn_global_load_lds(AS1(base + (size_t)R * DIM + cs * 8),
                                     AS3(buf + P * 512), 16, 0, 0);
  }
}

// Epilogue for one tile (two 32x32 chains): g = exp2(fma(log2e,dot,-log2e))
// == exp(dot-1) == exp(-d2/2) for unit rows; diagonal masked; off-diag x2.
// C/D layout (32x32): col=lane&31, row=(reg&3)+8*(reg>>2)+4*(lane>>5)
__device__ __forceinline__ void epilogue(const f32x16& acc0,
                                         const f32x16& acc1, int rtt, int ctt,
                                         int m, int n, int l31, int lhi,
                                         float& gsum) {
  float tsum = 0.0f;
  {  // chain 0: cols [n*64, +32); diag sub-block iff m == 2n
    const bool dsub = (rtt == ctt) && (m == 2 * n);
    if (dsub) {
#pragma unroll
      for (int r = 0; r < 16; ++r) {
        const float e = __builtin_amdgcn_exp2f(fmaf(L2E, acc0[r], -L2E));
        const int mloc = (r & 3) + 4 * lhi + 8 * (r >> 2);
        tsum += (mloc != l31) ? e : 0.0f;
      }
    } else {
#pragma unroll
      for (int r = 0; r < 16; ++r)
        tsum += __builtin_amdgcn_exp2f(fmaf(L2E, acc0[r], -L2E));
    }
  }
  {  // chain 1: cols [n*64+32, +32); diag sub-block iff m == 2n+1
    const bool dsub = (rtt == ctt) && (m == 2 * n + 1);
    if (dsub) {
#pragma unroll
      for (int r = 0; r < 16; ++r) {
        const float e = __builtin_amdgcn_exp2f(fmaf(L2E, acc1[r], -L2E));
        const int mloc = (r & 3) + 4 * lhi + 8 * (r >> 2);
        tsum += (mloc != l31) ? e : 0.0f;
      }
    } else {
#pragma unroll
      for (int r = 0; r < 16; ++r)
        tsum += __builtin_amdgcn_exp2f(fmaf(L2E, acc1[r], -L2E));
    }
  }
  gsum += (rtt == ctt) ? tsum : (tsum + tsum);  // off-diag mirrored x2
}

// MFMA block for one tile: 8 K-steps of {2 ds_read_b128 -> 2 MFMA}.
__device__ __forceinline__ void mfmaTile(const uint4* B4, int n, int l31,
                                         int lhi, const uint4* areg,
                                         f32x16& acc0, f32x16& acc1) {
  const int rb0 = n * 64 + l31;
  const int rb1 = n * 64 + 32 + l31;
#pragma unroll
  for (int ks = 0; ks < 8; ++ks) {
    const int kg = 2 * ks + lhi;
    const uint4 vb0 = B4[rb0 * 16 + (kg ^ (rb0 & 15))];
    const uint4 vb1 = B4[rb1 * 16 + (kg ^ (rb1 & 15))];
    const f16x8 af = __builtin_bit_cast(f16x8, areg[ks]);
    acc0 = __builtin_amdgcn_mfma_f32_32x32x16_f16(
        af, __builtin_bit_cast(f16x8, vb0), acc0, 0, 0, 0);
    acc1 = __builtin_amdgcn_mfma_f32_32x32x16_f16(
        af, __builtin_bit_cast(f16x8, vb1), acc1, 0, 0, 0);
  }
}

// ---------------------------------------------------------------------------
// Kernel 2: R9 structure + T15 epilogue pipelining. 512 blocks x 512 threads
// (8 waves, 4M x 2N); wave = 32 A-rows in regs x 64 B-cols from LDS (2
// ds_read_b128 -> 2 MFMA per K-step). B double-buffered (2 x 32 KiB), next
// tile staged with counted vmcnt(4) so loads fly across the barrier (T4).
// NEW: two named accumulator sets (A/B, static t&1 selection - rule #20);
// the end-of-tile barrier is moved BEFORE the epilogue (safe: every wave's
// ds_reads of buf[t] complete before its MFMA operand use, hence before the
// barrier), and the epilogue executed is the PREVIOUS tile's - its exp2/VALU
// stream overlaps other waves' staging and in-flight MFMAs instead of
// serializing behind them. Last tile's epilogue peeled after the loop.
// XCD swizzle (bid&7)*64+bid>>3 (bijective, 260 tiles/XCD). No atomics.
// ---------------------------------------------------------------------------
__global__ __launch_bounds__(512, 4) void fmicl_pairwise(
    const _Float16* __restrict__ zh, float* __restrict__ pairP) {
  __shared__ _Float16 B0[128 * DIM];  // 32 KiB
  __shared__ _Float16 B1[128 * DIM];  // 32 KiB
  __shared__ float wsum[8];

  const int tid = threadIdx.x;
  const int lane = tid & 63;
  const int wid = tid >> 6;
  const int l31 = lane & 31;
  const int lhi = lane >> 5;
  const int m = wid >> 1;  // 0..3: 32-row block of the band
  const int n = wid & 1;   // 0..1: 64-col half of the tile

  // XCD-chunked swizzle (512 = 8*64, bijective; 260 tiles per XCD)
  const int c = (blockIdx.x & 7) * 64 + (blockIdx.x >> 3);
  const int nx = (c + 15) >> 4;  // len-5 chunks before c
  const int base = 4 * c + nx;
  const int len = 4 + ((c & 15) == 0 ? 1 : 0);

  // ---- decode base -> (rt, ct); C(r) = r*NT - r(r-1)/2 ----
  int rt = (int)(64.5f - sqrtf(64.5f * 64.5f - 2.0f * (float)base));
  if (rt < 0) rt = 0;
  while (rt > 0 && (rt * NT - (rt * (rt - 1)) / 2) > base) --rt;
  while (((rt + 1) * NT - ((rt + 1) * rt) / 2) <= base) ++rt;
  int ctt = rt + (base - (rt * NT - (rt * (rt - 1)) / 2));
  int rtt = rt;

  stageB(zh, B0, ctt, wid, lane);  // prologue stage of tile 0

  uint4 areg[8];
  int cur_rt = -1;
  float gsum = 0.0f;
  f32x16 accA0 = {}, accA1 = {}, accB0 = {}, accB1 = {};
  int prt = 0, pct = 0;

#pragma unroll 1
  for (int t = 0; t < len; ++t) {
    // ---- A-regs: reload only on band crossing ----
    if (rtt != cur_rt) {
      cur_rt = rtt;
      const uint4* ar =
          (const uint4*)(zh + (size_t)((rtt << 7) + m * 32 + l31) * DIM);
#pragma unroll
      for (int ks = 0; ks < 8; ++ks) areg[ks] = ar[2 * ks + lhi];
    }
    // ---- next tile coords; issue its stage before computing this one ----
    int nrt = rtt, nct = ctt + 1;
    if (nct == NT) { ++nrt; nct = nrt; }
    if (t + 1 < len) {
      stageB(zh, (t & 1) ? B0 : B1, nct, wid, lane);
      asm volatile("s_waitcnt vmcnt(4)" ::: "memory");  // tile-t data ready
    } else {
      asm volatile("s_waitcnt vmcnt(0)" ::: "memory");
    }
    __builtin_amdgcn_s_barrier();
    __builtin_amdgcn_sched_barrier(0);

    // ---- MFMA(t) into the current acc set; epilogue(t-1) on the other ----
    const uint4* B4 = (const uint4*)((t & 1) ? B1 : B0);
    if ((t & 1) == 0) {
      accA0 = {};
      accA1 = {};
      mfmaTile(B4, n, l31, lhi, areg, accA0, accA1);
      __builtin_amdgcn_s_barrier();  // buf[t] reads done -> restage safe
      if (t > 0) epilogue(accB0, accB1, prt, pct, m, n, l31, lhi, gsum);
    } else {
      accB0 = {};
      accB1 = {};
      mfmaTile(B4, n, l31, lhi, areg, accB0, accB1);
      __builtin_amdgcn_s_barrier();
      epilogue(accA0, accA1, prt, pct, m, n, l31, lhi, gsum);
    }
    prt = rtt;
    pct = ctt;
    rtt = nrt;
    ctt = nct;
  }
  // ---- peeled epilogue of the final tile ----
  if ((len & 1) == 0)
    epilogue(accB0, accB1, prt, pct, m, n, l31, lhi, gsum);  // len even: last in B
  else
    epilogue(accA0, accA1, prt, pct, m, n, l31, lhi, gsum);  // len odd: last in A

  // ---- per-block reduction -> pairP[c] ----
#pragma unroll
  for (int off = 32; off; off >>= 1) gsum += __shfl_xor(gsum, off);
  if (lane == 0) wsum[wid] = gsum;
  __syncthreads();
  if (tid == 0) {
    float s = 0.0f;
#pragma unroll
    for (int q = 0; q < 8; ++q) s += wsum[q];
    pairP[c] = s;
  }
}

// ---------------------------------------------------------------------------
// Kernel 3: single-block fused reduce + assemble scalar (deterministic
// fixed-order tree). star_neg = g + EPS exactly, so
// star_mean = negSum/(N(N-1)) + EPS.
// ---------------------------------------------------------------------------
__global__ void fmicl_reduce(const float* __restrict__ pairP,
                             const float* __restrict__ sposB,
                             float* __restrict__ out) {
  const int t = threadIdx.x;  // 1024 threads = 16 waves
  double nsum = (t < NBLK) ? (double)pairP[t] : 0.0;
  double psum = (t < 512) ? (double)sposB[t] : 0.0;
#pragma unroll
  for (int off = 32; off; off >>= 1) {
    nsum += __shfl_xor(nsum, off);
    psum += __shfl_xor(psum, off);
  }
  __shared__ double ls[2][16];
  const int lane = t & 63;
  const int wid = t >> 6;
  if (lane == 0) {
    ls[0][wid] = nsum;
    ls[1][wid] = psum;
  }
  __syncthreads();
  if (t == 0) {
    double nn = 0.0, pp = 0.0;
#pragma unroll
    for (int q = 0; q < 16; ++q) {
      nn += ls[0][q];
      pp += ls[1][q];
    }
    const double pos_mean = pp / (double)NROWS;
    const double star_mean = nn / ((double)NROWS * (double)(NROWS - 1)) + 1e-8;
    out[0] = (float)(-pos_mean + 1.5 * star_mean);
  }
}

extern "C" void kernel_launch(void* const* d_in, const int* in_sizes, int n_in,
                              void* d_out, int out_size, void* d_ws,
                              size_t ws_size, hipStream_t stream) {
  const float* z1 = (const float*)d_in[0];
  const float* z2 = (const float*)d_in[1];
  float* out = (float*)d_out;
  char* ws = (char*)d_ws;

  // ws layout (every slot rewritten every call; no memset needed):
  //   [0)     pairP float[512]    (2048 B, pad to 4096)
  //   [4096)  sposB float[512]    (2048 B)
  //   [6144)  zh    f16[8192*128] (2 MiB, 16B-aligned)
  float* pairP = (float*)(ws + 0);
  float* sposB = (float*)(ws + 4096);
  _Float16* zh = (_Float16*)(ws + 6144);

  fmicl_normalize<<<512, 1024, 0, stream>>>(z1, z2, zh, sposB);
  fmicl_pairwise<<<NBLK, 512, 0, stream>>>(zh, pairP);
  fmicl_reduce<<<1, 1024, 0, stream>>>(pairP, sposB, out);
}

// Round 15
// 41.577 us; speedup vs baseline: 1.6002x; 1.6002x over previous
//
#include <hip/hip_runtime.h>

#define NROWS 8192
#define DIM 128
#define NT 64      // 128x128 tiles per side
#define NBLK 512   // pairwise blocks; block c owns 4(+1) consecutive tiles

typedef _Float16 f16x8 __attribute__((ext_vector_type(8)));
typedef _Float16 f16x2 __attribute__((ext_vector_type(2)));
typedef float f32x16 __attribute__((ext_vector_type(16)));

#define L2E 1.4426950408889634f  // log2(e)

#define AS1(p) ((const __attribute__((address_space(1))) void*)(p))
#define AS3(p) ((__attribute__((address_space(3))) void*)(p))

// ---------------------------------------------------------------------------
// Kernel 1: per-row L2 normalize (fp32, as reference). R9-verified body +
// ticket-counter reset (runs before pairwise in stream order, so the reset
// is visible at the next dispatch boundary - R4-proven pattern).
// ---------------------------------------------------------------------------
__global__ __launch_bounds__(1024) void fmicl_normalize(
    const float* __restrict__ z1, const float* __restrict__ z2,
    _Float16* __restrict__ zh, float* __restrict__ sposB,
    unsigned int* __restrict__ cnt) {
  if (blockIdx.x == 0 && threadIdx.x < 9) {
    // cnt[0..7]: per-XCD-group arrival counters (one 64B line each);
    // cnt[8*16]: second-level counter (own line)
    cnt[threadIdx.x * 16] = 0u;
  }
  const int wid = threadIdx.x >> 6;
  const int lane = threadIdx.x & 63;
  const int row = blockIdx.x * 16 + wid;
  const float2 a = ((const float2*)(z1 + (size_t)row * DIM))[lane];
  const float2 b = ((const float2*)(z2 + (size_t)row * DIM))[lane];
  float s1 = a.x * a.x + a.y * a.y;
  float s2 = b.x * b.x + b.y * b.y;
#pragma unroll
  for (int off = 32; off; off >>= 1) {
    s1 += __shfl_xor(s1, off);
    s2 += __shfl_xor(s2, off);
  }
  const float inv1 = 1.0f / fmaxf(sqrtf(s1), 1e-12f);
  const float inv2 = 1.0f / fmaxf(sqrtf(s2), 1e-12f);
  const float n1x = a.x * inv1, n1y = a.y * inv1;
  const float n2x = b.x * inv2, n2y = b.y * inv2;
  const float dx = n1x - n2x, dy = n1y - n2y;
  float dp = dx * dx + dy * dy;
#pragma unroll
  for (int off = 32; off; off >>= 1) dp += __shfl_xor(dp, off);
  f16x2 h;
  h.x = (_Float16)n1x;
  h.y = (_Float16)n1y;
  *(f16x2*)(zh + (size_t)row * DIM + 2 * lane) = h;
  __shared__ float sposL[16];
  if (lane == 0)
    sposL[wid] = logf(expf(-0.5f * dp) + 1e-8f) + 1.0f;  // f'(g_pos)
  __syncthreads();
  if (threadIdx.x == 0) {
    float s = 0.0f;
#pragma unroll
    for (int k = 0; k < 16; ++k) s += sposL[k];
    sposB[blockIdx.x] = s;
  }
}

// ---------------------------------------------------------------------------
// Stage one 128-row B panel (32 KiB) into LDS via global_load_lds width=16.
// LDS dest linear; global source pre-swizzled (granule col ^= row&15);
// read side applies the same XOR (involution; rounds 3-12 verified,
// 0 bank conflicts). 4 VMEM instructions per wave.
// ---------------------------------------------------------------------------
__device__ __forceinline__ void stageB(const _Float16* __restrict__ zh,
                                       _Float16* buf, int ct, int wid,
                                       int lane) {
  const _Float16* base = zh + ((size_t)ct << 7) * DIM;
#pragma unroll
  for (int it = 0; it < 4; ++it) {
    const int P = it * 8 + wid;          // wave-uniform 4-row group 0..31
    const int R = P * 4 + (lane >> 4);   // row 0..127
    const int cs = (lane & 15) ^ (R & 15);
    __builtin_amdgcn_global_load_lds(AS1(base + (size_t)R * DIM + cs * 8),
                                     AS3(buf + P * 512), 16, 0, 0);
  }
}

// ---------------------------------------------------------------------------
// Kernel 2: R9 pairwise (champion, byte-identical compute body) + last-block
// fused reduce. Per block: 8 waves (4M x 2N), wave = 32 A-rows in regs x 64
// B-cols from LDS (2 ds_read_b128 -> 2 MFMA per K-step); B double-buffered
// (2 x 32 KiB), next tile staged with counted vmcnt(4) (T4). Epilogue:
// g = exp2(fma(log2e,dot,-log2e)) == exp(-d2/2) for unit rows; diagonal
// masked; off-diag tiles x2. XCD swizzle (bid&7)*64+bid>>3 (bijective).
// END: release-fence + two-level ticket (8 per-group counters on separate
// cachelines, 64 staggered arrivals each ~overlapped with compute tail;
// second level of 8) - avoids R4's 2080-deep single-line atomic chain.
// The globally-last block acquire-fences and reduces pairP+sposB -> out.
// Fence/ticket/plain-read semantics are R4-proven on this HW (absmax 0.0).
// ---------------------------------------------------------------------------
__global__ __launch_bounds__(512, 4) void fmicl_pairwise(
    const _Float16* __restrict__ zh, float* __restrict__ pairP,
    const float* __restrict__ sposB, unsigned int* __restrict__ cnt,
    float* __restrict__ out) {
  __shared__ _Float16 B0[128 * DIM];  // 32 KiB
  __shared__ _Float16 B1[128 * DIM];  // 32 KiB
  __shared__ float wsum[8];
  __shared__ int amLast;

  const int tid = threadIdx.x;
  const int lane = tid & 63;
  const int wid = tid >> 6;
  const int l31 = lane & 31;
  const int lhi = lane >> 5;
  const int m = wid >> 1;  // 0..3: 32-row block of the band
  const int n = wid & 1;   // 0..1: 64-col half of the tile

  // XCD-chunked swizzle (512 = 8*64, bijective; 260 tiles per XCD)
  const int c = (blockIdx.x & 7) * 64 + (blockIdx.x >> 3);
  const int nx = (c + 15) >> 4;  // len-5 chunks before c
  const int base = 4 * c + nx;
  const int len = 4 + ((c & 15) == 0 ? 1 : 0);

  // ---- decode base -> (rt, ct); C(r) = r*NT - r(r-1)/2 ----
  int rt = (int)(64.5f - sqrtf(64.5f * 64.5f - 2.0f * (float)base));
  if (rt < 0) rt = 0;
  while (rt > 0 && (rt * NT - (rt * (rt - 1)) / 2) > base) --rt;
  while (((rt + 1) * NT - ((rt + 1) * rt) / 2) <= base) ++rt;
  int ctt = rt + (base - (rt * NT - (rt * (rt - 1)) / 2));
  int rtt = rt;

  stageB(zh, B0, ctt, wid, lane);  // prologue stage of tile 0

  uint4 areg[8];
  int cur_rt = -1;
  float gsum = 0.0f;

#pragma unroll 1
  for (int t = 0; t < len; ++t) {
    // ---- A-regs: reload only on band crossing ----
    if (rtt != cur_rt) {
      cur_rt = rtt;
      const uint4* ar =
          (const uint4*)(zh + (size_t)((rtt << 7) + m * 32 + l31) * DIM);
#pragma unroll
      for (int ks = 0; ks < 8; ++ks) areg[ks] = ar[2 * ks + lhi];
    }
    // ---- next tile coords; issue its stage before computing this one ----
    int nrt = rtt, nct = ctt + 1;
    if (nct == NT) { ++nrt; nct = nrt; }
    if (t + 1 < len) {
      stageB(zh, (t & 1) ? B0 : B1, nct, wid, lane);
      asm volatile("s_waitcnt vmcnt(4)" ::: "memory");  // tile-t data ready
    } else {
      asm volatile("s_waitcnt vmcnt(0)" ::: "memory");
    }
    __builtin_amdgcn_s_barrier();
    __builtin_amdgcn_sched_barrier(0);

    // ---- compute: 8 K-steps, 2 B-reads -> 2 MFMA (A from registers) ----
    const uint4* B4 = (const uint4*)((t & 1) ? B1 : B0);
    const int rb0 = n * 64 + l31;
    const int rb1 = n * 64 + 32 + l31;
    f32x16 acc0 = {}, acc1 = {};
#pragma unroll
    for (int ks = 0; ks < 8; ++ks) {
      const int kg = 2 * ks + lhi;
      const uint4 vb0 = B4[rb0 * 16 + (kg ^ (rb0 & 15))];
      const uint4 vb1 = B4[rb1 * 16 + (kg ^ (rb1 & 15))];
      const f16x8 af = __builtin_bit_cast(f16x8, areg[ks]);
      acc0 = __builtin_amdgcn_mfma_f32_32x32x16_f16(
          af, __builtin_bit_cast(f16x8, vb0), acc0, 0, 0, 0);
      acc1 = __builtin_amdgcn_mfma_f32_32x32x16_f16(
          af, __builtin_bit_cast(f16x8, vb1), acc1, 0, 0, 0);
    }

    // ---- epilogue: g = exp2(log2e*dot - log2e) == exp(-d2/2) ----
    // C/D layout (32x32): col=lane&31, row=(reg&3)+8*(reg>>2)+4*(lane>>5)
    float tsum = 0.0f;
    {  // chain 0: cols [n*64, +32); diag sub-block iff m == 2n
      const bool dsub = (rtt == ctt) && (m == 2 * n);
      if (dsub) {
#pragma unroll
        for (int r = 0; r < 16; ++r) {
          const float e = __builtin_amdgcn_exp2f(fmaf(L2E, acc0[r], -L2E));
          const int mloc = (r & 3) + 4 * lhi + 8 * (r >> 2);
          tsum += (mloc != l31) ? e : 0.0f;
        }
      } else {
#pragma unroll
        for (int r = 0; r < 16; ++r)
          tsum += __builtin_amdgcn_exp2f(fmaf(L2E, acc0[r], -L2E));
      }
    }
    {  // chain 1: cols [n*64+32, +32); diag sub-block iff m == 2n+1
      const bool dsub = (rtt == ctt) && (m == 2 * n + 1);
      if (dsub) {
#pragma unroll
        for (int r = 0; r < 16; ++r) {
          const float e = __builtin_amdgcn_exp2f(fmaf(L2E, acc1[r], -L2E));
          const int mloc = (r & 3) + 4 * lhi + 8 * (r >> 2);
          tsum += (mloc != l31) ? e : 0.0f;
        }
      } else {
#pragma unroll
        for (int r = 0; r < 16; ++r)
          tsum += __builtin_amdgcn_exp2f(fmaf(L2E, acc1[r], -L2E));
      }
    }
    gsum += (rtt == ctt) ? tsum : (tsum + tsum);  // off-diag mirrored x2

    __builtin_amdgcn_s_barrier();  // buf reads done before its re-stage
    rtt = nrt;
    ctt = nct;
  }

  // ---- per-block reduction -> pairP[c]; two-level ticket ----
#pragma unroll
  for (int off = 32; off; off >>= 1) gsum += __shfl_xor(gsum, off);
  if (lane == 0) wsum[wid] = gsum;
  __syncthreads();
  if (tid == 0) {
    float s = 0.0f;
#pragma unroll
    for (int q = 0; q < 8; ++q) s += wsum[q];
    pairP[c] = s;
    __threadfence();  // release the partial (R4-proven)
    int last = 0;
    const unsigned int r1 =
        atomicAdd(&cnt[(blockIdx.x & 7) * 16], 1u);  // 64 arrivals/line
    if (r1 == 63u) {
      const unsigned int r2 = atomicAdd(&cnt[8 * 16], 1u);  // 8 arrivals
      last = (r2 == 7u) ? 1 : 0;
    }
    amLast = last;
  }
  __syncthreads();

  // ---- globally-last block: acquire + fixed-order reduce + assemble ----
  if (amLast) {
    __threadfence();  // acquire all partials (R4-proven)
    double nsum = (double)pairP[tid];       // 512 threads, 512 partials
    double psum = (double)sposB[tid];       // 512 normalize partials
#pragma unroll
    for (int off = 32; off; off >>= 1) {
      nsum += __shfl_xor(nsum, off);
      psum += __shfl_xor(psum, off);
    }
    __shared__ double ls[2][8];
    if (lane == 0) {
      ls[0][wid] = nsum;
      ls[1][wid] = psum;
    }
    __syncthreads();
    if (tid == 0) {
      double nn = 0.0, pp = 0.0;
#pragma unroll
      for (int q = 0; q < 8; ++q) {
        nn += ls[0][q];
        pp += ls[1][q];
      }
      const double pos_mean = pp / (double)NROWS;
      // star_neg = g + EPS exactly -> star_mean = negSum/(N(N-1)) + EPS
      const double star_mean =
          nn / ((double)NROWS * (double)(NROWS - 1)) + 1e-8;
      out[0] = (float)(-pos_mean + 1.5 * star_mean);
    }
  }
}

extern "C" void kernel_launch(void* const* d_in, const int* in_sizes, int n_in,
                              void* d_out, int out_size, void* d_ws,
                              size_t ws_size, hipStream_t stream) {
  const float* z1 = (const float*)d_in[0];
  const float* z2 = (const float*)d_in[1];
  float* out = (float*)d_out;
  char* ws = (char*)d_ws;

  // ws layout (pairP/sposB/zh rewritten every call; cnt reset by normalize):
  //   [0)     pairP float[512]     (2048 B)
  //   [2048)  cnt   uint[9*16]     (9 x 64B lines: 8 group ctrs + 1 final)
  //   [4096)  sposB float[512]     (2048 B)
  //   [6144)  zh    f16[8192*128]  (2 MiB, 16B-aligned)
  float* pairP = (float*)(ws + 0);
  unsigned int* cnt = (unsigned int*)(ws + 2048);
  float* sposB = (float*)(ws + 4096);
  _Float16* zh = (_Float16*)(ws + 6144);

  fmicl_normalize<<<512, 1024, 0, stream>>>(z1, z2, zh, sposB, cnt);
  fmicl_pairwise<<<NBLK, 512, 0, stream>>>(zh, pairP, sposB, cnt, out);
}

// Round 16
// 29.134 us; speedup vs baseline: 2.2837x; 1.4271x over previous
//
#include <hip/hip_runtime.h>

#define NROWS 8192
#define DIM 128
#define NT 64      // 128x128 tiles per side
#define NBLK 512   // pairwise blocks; block c owns 4(+1) consecutive tiles

typedef _Float16 f16x8 __attribute__((ext_vector_type(8)));
typedef _Float16 f16x4 __attribute__((ext_vector_type(4)));
typedef float f32x16 __attribute__((ext_vector_type(16)));

#define L2E 1.4426950408889634f  // log2(e)

#define AS1(p) ((const __attribute__((address_space(1))) void*)(p))
#define AS3(p) ((__attribute__((address_space(3))) void*)(p))

// ---------------------------------------------------------------------------
// Kernel 1: per-row L2 normalize (fp32, as reference), float4-vectorized.
// 1024 threads = 16 waves; each wave handles TWO rows (lanes 0-31 row A,
// lanes 32-63 row B; 32 lanes x float4 = 128 floats/row -> 16 B/lane, the
// coalescing sweet spot). Shuffle reductions use XOR offsets <32 so they
// stay within each half-wave. 256 blocks x 32 rows. Emits zh (f16
// normalized z1) and sposB (per-block partial of the positive term, 256
// floats). ||n1||^2 = 1 +- 3e-7 -> absorbed into the epilogue constant
// (rounds 6-15 verified). No atomics.
// ---------------------------------------------------------------------------
__global__ __launch_bounds__(1024) void fmicl_normalize(
    const float* __restrict__ z1, const float* __restrict__ z2,
    _Float16* __restrict__ zh, float* __restrict__ sposB) {
  const int wid = threadIdx.x >> 6;
  const int lane = threadIdx.x & 63;
  const int half = lane >> 5;   // 0/1: which of the wave's two rows
  const int li = lane & 31;     // position within the row (x float4)
  const int row = blockIdx.x * 32 + wid * 2 + half;

  const float4 a = ((const float4*)(z1 + (size_t)row * DIM))[li];
  const float4 b = ((const float4*)(z2 + (size_t)row * DIM))[li];
  float s1 = a.x * a.x + a.y * a.y + a.z * a.z + a.w * a.w;
  float s2 = b.x * b.x + b.y * b.y + b.z * b.z + b.w * b.w;
#pragma unroll
  for (int off = 16; off; off >>= 1) {  // within-half reduction (32 lanes)
    s1 += __shfl_xor(s1, off);
    s2 += __shfl_xor(s2, off);
  }
  const float inv1 = 1.0f / fmaxf(sqrtf(s1), 1e-12f);
  const float inv2 = 1.0f / fmaxf(sqrtf(s2), 1e-12f);
  const float n1x = a.x * inv1, n1y = a.y * inv1, n1z = a.z * inv1,
              n1w = a.w * inv1;
  const float dx = n1x - b.x * inv2, dy = n1y - b.y * inv2,
              dz = n1z - b.z * inv2, dw = n1w - b.w * inv2;
  float dp = dx * dx + dy * dy + dz * dz + dw * dw;
#pragma unroll
  for (int off = 16; off; off >>= 1) dp += __shfl_xor(dp, off);

  f16x4 h;
  h.x = (_Float16)n1x;
  h.y = (_Float16)n1y;
  h.z = (_Float16)n1z;
  h.w = (_Float16)n1w;
  *(f16x4*)(zh + (size_t)row * DIM + 4 * li) = h;

  __shared__ float sposL[32];
  if (li == 0)
    sposL[wid * 2 + half] = logf(expf(-0.5f * dp) + 1e-8f) + 1.0f;  // f'(g_pos)
  __syncthreads();
  if (threadIdx.x == 0) {
    float s = 0.0f;
#pragma unroll
    for (int k = 0; k < 32; ++k) s += sposL[k];
    sposB[blockIdx.x] = s;
  }
}

// ---------------------------------------------------------------------------
// Stage one 128-row B panel (32 KiB) into LDS via global_load_lds width=16.
// LDS dest linear; global source pre-swizzled (granule col ^= row&15);
// read side applies the same XOR (involution; rounds 3-15 verified,
// 0 bank conflicts). 4 VMEM instructions per wave.
// ---------------------------------------------------------------------------
__device__ __forceinline__ void stageB(const _Float16* __restrict__ zh,
                                       _Float16* buf, int ct, int wid,
                                       int lane) {
  const _Float16* base = zh + ((size_t)ct << 7) * DIM;
#pragma unroll
  for (int it = 0; it < 4; ++it) {
    const int P = it * 8 + wid;          // wave-uniform 4-row group 0..31
    const int R = P * 4 + (lane >> 4);   // row 0..127
    const int cs = (lane & 15) ^ (R & 15);
    __builtin_amdgcn_global_load_lds(AS1(base + (size_t)R * DIM + cs * 8),
                                     AS3(buf + P * 512), 16, 0, 0);
  }
}

// ---------------------------------------------------------------------------
// Kernel 2: champion pairwise (round 9, byte-identical). 512 blocks x 512
// threads (8 waves, 4M x 2N); wave = 32 A-rows in regs x 64 B-cols from LDS
// (2 ds_read_b128 -> 2 MFMA per K-step). B double-buffered (2 x 32 KiB);
// next tile staged before compute with counted s_waitcnt vmcnt(4) so its
// loads stay in flight across the barrier (T4). ~60 VGPR -> 2 blocks/CU.
// Epilogue: g = exp2(fma(log2e,dot,-log2e)) == exp(-d2/2) for unit rows;
// diagonal masked; off-diag tiles x2. Block c owns tiles [4c+nx, +len) of
// the flat triangular list (len=5 when c%16==0). XCD swizzle
// (bid&7)*64+bid>>3 (bijective, 260 tiles/XCD). No atomics.
// ---------------------------------------------------------------------------
__global__ __launch_bounds__(512, 4) void fmicl_pairwise(
    const _Float16* __restrict__ zh, float* __restrict__ pairP) {
  __shared__ _Float16 B0[128 * DIM];  // 32 KiB
  __shared__ _Float16 B1[128 * DIM];  // 32 KiB
  __shared__ float wsum[8];

  const int tid = threadIdx.x;
  const int lane = tid & 63;
  const int wid = tid >> 6;
  const int l31 = lane & 31;
  const int lhi = lane >> 5;
  const int m = wid >> 1;  // 0..3: 32-row block of the band
  const int n = wid & 1;   // 0..1: 64-col half of the tile

  // XCD-chunked swizzle (512 = 8*64, bijective; 260 tiles per XCD)
  const int c = (blockIdx.x & 7) * 64 + (blockIdx.x >> 3);
  const int nx = (c + 15) >> 4;  // len-5 chunks before c
  const int base = 4 * c + nx;
  const int len = 4 + ((c & 15) == 0 ? 1 : 0);

  // ---- decode base -> (rt, ct); C(r) = r*NT - r(r-1)/2 ----
  int rt = (int)(64.5f - sqrtf(64.5f * 64.5f - 2.0f * (float)base));
  if (rt < 0) rt = 0;
  while (rt > 0 && (rt * NT - (rt * (rt - 1)) / 2) > base) --rt;
  while (((rt + 1) * NT - ((rt + 1) * rt) / 2) <= base) ++rt;
  int ctt = rt + (base - (rt * NT - (rt * (rt - 1)) / 2));
  int rtt = rt;

  stageB(zh, B0, ctt, wid, lane);  // prologue stage of tile 0

  uint4 areg[8];
  int cur_rt = -1;
  float gsum = 0.0f;

#pragma unroll 1
  for (int t = 0; t < len; ++t) {
    // ---- A-regs: reload only on band crossing ----
    if (rtt != cur_rt) {
      cur_rt = rtt;
      const uint4* ar =
          (const uint4*)(zh + (size_t)((rtt << 7) + m * 32 + l31) * DIM);
#pragma unroll
      for (int ks = 0; ks < 8; ++ks) areg[ks] = ar[2 * ks + lhi];
    }
    // ---- next tile coords; issue its stage before computing this one ----
    int nrt = rtt, nct = ctt + 1;
    if (nct == NT) { ++nrt; nct = nrt; }
    if (t + 1 < len) {
      stageB(zh, (t & 1) ? B0 : B1, nct, wid, lane);
      // all but the newest 4 loads (= next tile's stage) complete: current
      // B-panel + any A-reload are in. Next stage flies across the barrier.
      asm volatile("s_waitcnt vmcnt(4)" ::: "memory");
    } else {
      asm volatile("s_waitcnt vmcnt(0)" ::: "memory");
    }
    __builtin_amdgcn_s_barrier();
    __builtin_amdgcn_sched_barrier(0);

    // ---- compute: 8 K-steps, 2 B-reads -> 2 MFMA (A from registers) ----
    const uint4* B4 = (const uint4*)((t & 1) ? B1 : B0);
    const int rb0 = n * 64 + l31;
    const int rb1 = n * 64 + 32 + l31;
    f32x16 acc0 = {}, acc1 = {};
#pragma unroll
    for (int ks = 0; ks < 8; ++ks) {
      const int kg = 2 * ks + lhi;
      const uint4 vb0 = B4[rb0 * 16 + (kg ^ (rb0 & 15))];
      const uint4 vb1 = B4[rb1 * 16 + (kg ^ (rb1 & 15))];
      const f16x8 af = __builtin_bit_cast(f16x8, areg[ks]);
      acc0 = __builtin_amdgcn_mfma_f32_32x32x16_f16(
          af, __builtin_bit_cast(f16x8, vb0), acc0, 0, 0, 0);
      acc1 = __builtin_amdgcn_mfma_f32_32x32x16_f16(
          af, __builtin_bit_cast(f16x8, vb1), acc1, 0, 0, 0);
    }

    // ---- epilogue: g = exp2(log2e*dot - log2e) == exp(-d2/2) ----
    // C/D layout (32x32): col=lane&31, row=(reg&3)+8*(reg>>2)+4*(lane>>5)
    float tsum = 0.0f;
    {  // chain 0: cols [n*64, +32); diag sub-block iff m == 2n
      const bool dsub = (rtt == ctt) && (m == 2 * n);
      if (dsub) {
#pragma unroll
        for (int r = 0; r < 16; ++r) {
          const float e = __builtin_amdgcn_exp2f(fmaf(L2E, acc0[r], -L2E));
          const int mloc = (r & 3) + 4 * lhi + 8 * (r >> 2);
          tsum += (mloc != l31) ? e : 0.0f;
        }
      } else {
#pragma unroll
        for (int r = 0; r < 16; ++r)
          tsum += __builtin_amdgcn_exp2f(fmaf(L2E, acc0[r], -L2E));
      }
    }
    {  // chain 1: cols [n*64+32, +32); diag sub-block iff m == 2n+1
      const bool dsub = (rtt == ctt) && (m == 2 * n + 1);
      if (dsub) {
#pragma unroll
        for (int r = 0; r < 16; ++r) {
          const float e = __builtin_amdgcn_exp2f(fmaf(L2E, acc1[r], -L2E));
          const int mloc = (r & 3) + 4 * lhi + 8 * (r >> 2);
          tsum += (mloc != l31) ? e : 0.0f;
        }
      } else {
#pragma unroll
        for (int r = 0; r < 16; ++r)
          tsum += __builtin_amdgcn_exp2f(fmaf(L2E, acc1[r], -L2E));
      }
    }
    gsum += (rtt == ctt) ? tsum : (tsum + tsum);  // off-diag mirrored x2

    __builtin_amdgcn_s_barrier();  // buf reads done before its re-stage
    rtt = nrt;
    ctt = nct;
  }

  // ---- per-block reduction -> pairP[c] ----
#pragma unroll
  for (int off = 32; off; off >>= 1) gsum += __shfl_xor(gsum, off);
  if (lane == 0) wsum[wid] = gsum;
  __syncthreads();
  if (tid == 0) {
    float s = 0.0f;
#pragma unroll
    for (int q = 0; q < 8; ++q) s += wsum[q];
    pairP[c] = s;
  }
}

// ---------------------------------------------------------------------------
// Kernel 3: single-block fused reduce + assemble scalar (deterministic
// fixed-order tree). star_neg = g + EPS exactly, so
// star_mean = negSum/(N(N-1)) + EPS.
// ---------------------------------------------------------------------------
__global__ void fmicl_reduce(const float* __restrict__ pairP,
                             const float* __restrict__ sposB,
                             float* __restrict__ out) {
  const int t = threadIdx.x;  // 1024 threads = 16 waves
  double nsum = (t < NBLK) ? (double)pairP[t] : 0.0;
  double psum = (t < 256) ? (double)sposB[t] : 0.0;
#pragma unroll
  for (int off = 32; off; off >>= 1) {
    nsum += __shfl_xor(nsum, off);
    psum += __shfl_xor(psum, off);
  }
  __shared__ double ls[2][16];
  const int lane = t & 63;
  const int wid = t >> 6;
  if (lane == 0) {
    ls[0][wid] = nsum;
    ls[1][wid] = psum;
  }
  __syncthreads();
  if (t == 0) {
    double nn = 0.0, pp = 0.0;
#pragma unroll
    for (int q = 0; q < 16; ++q) {
      nn += ls[0][q];
      pp += ls[1][q];
    }
    const double pos_mean = pp / (double)NROWS;
    const double star_mean = nn / ((double)NROWS * (double)(NROWS - 1)) + 1e-8;
    out[0] = (float)(-pos_mean + 1.5 * star_mean);
  }
}

extern "C" void kernel_launch(void* const* d_in, const int* in_sizes, int n_in,
                              void* d_out, int out_size, void* d_ws,
                              size_t ws_size, hipStream_t stream) {
  const float* z1 = (const float*)d_in[0];
  const float* z2 = (const float*)d_in[1];
  float* out = (float*)d_out;
  char* ws = (char*)d_ws;

  // ws layout (every slot rewritten every call; no memset needed):
  //   [0)     pairP float[512]    (2048 B, pad to 4096)
  //   [4096)  sposB float[256]    (1024 B)
  //   [6144)  zh    f16[8192*128] (2 MiB, 16B-aligned)
  float* pairP = (float*)(ws + 0);
  float* sposB = (float*)(ws + 4096);
  _Float16* zh = (_Float16*)(ws + 6144);

  fmicl_normalize<<<256, 1024, 0, stream>>>(z1, z2, zh, sposB);
  fmicl_pairwise<<<NBLK, 512, 0, stream>>>(zh, pairP);
  fmicl_reduce<<<1, 1024, 0, stream>>>(pairP, sposB, out);
}

// Round 17
// 28.871 us; speedup vs baseline: 2.3045x; 1.0091x over previous
//
#include <hip/hip_runtime.h>

#define NROWS 8192
#define DIM 128
#define NT 64      // 128x128 tiles per side
#define NBLK 512   // pairwise blocks; block c owns 4(+1) consecutive tiles

typedef _Float16 f16x8 __attribute__((ext_vector_type(8)));
typedef _Float16 f16x4 __attribute__((ext_vector_type(4)));
typedef float f32x16 __attribute__((ext_vector_type(16)));

#define L2E 1.4426950408889634f      // log2(e)
#define SQRTL2E 1.2011224087864498f  // sqrt(log2(e))

#define AS1(p) ((const __attribute__((address_space(1))) void*)(p))
#define AS3(p) ((__attribute__((address_space(3))) void*)(p))

// ---------------------------------------------------------------------------
// Kernel 1: per-row L2 normalize (fp32, as reference), float4-vectorized
// (R16-verified). NEW: stored zh is PRE-SCALED by sqrt(log2e), so the Gram
// MFMA produces L2E*dot directly and the epilogue fma disappears (the scale
// and the -L2E constant both ride the matrix pipe for free).
// Each wave: two rows (lanes 0-31 / 32-63), 16 B/lane. 256 blocks x 32 rows.
// sposB: per-block partial of the positive term (256 floats). No atomics.
// ---------------------------------------------------------------------------
__global__ __launch_bounds__(1024) void fmicl_normalize(
    const float* __restrict__ z1, const float* __restrict__ z2,
    _Float16* __restrict__ zh, float* __restrict__ sposB) {
  const int wid = threadIdx.x >> 6;
  const int lane = threadIdx.x & 63;
  const int half = lane >> 5;   // 0/1: which of the wave's two rows
  const int li = lane & 31;     // position within the row (x float4)
  const int row = blockIdx.x * 32 + wid * 2 + half;

  const float4 a = ((const float4*)(z1 + (size_t)row * DIM))[li];
  const float4 b = ((const float4*)(z2 + (size_t)row * DIM))[li];
  float s1 = a.x * a.x + a.y * a.y + a.z * a.z + a.w * a.w;
  float s2 = b.x * b.x + b.y * b.y + b.z * b.z + b.w * b.w;
#pragma unroll
  for (int off = 16; off; off >>= 1) {  // within-half reduction (32 lanes)
    s1 += __shfl_xor(s1, off);
    s2 += __shfl_xor(s2, off);
  }
  const float inv1 = 1.0f / fmaxf(sqrtf(s1), 1e-12f);
  const float inv2 = 1.0f / fmaxf(sqrtf(s2), 1e-12f);
  const float n1x = a.x * inv1, n1y = a.y * inv1, n1z = a.z * inv1,
              n1w = a.w * inv1;
  const float dx = n1x - b.x * inv2, dy = n1y - b.y * inv2,
              dz = n1z - b.z * inv2, dw = n1w - b.w * inv2;
  float dp = dx * dx + dy * dy + dz * dz + dw * dw;
#pragma unroll
  for (int off = 16; off; off >>= 1) dp += __shfl_xor(dp, off);

  f16x4 h;  // store n1 * sqrt(log2e): Gram dot comes out pre-multiplied
  h.x = (_Float16)(n1x * SQRTL2E);
  h.y = (_Float16)(n1y * SQRTL2E);
  h.z = (_Float16)(n1z * SQRTL2E);
  h.w = (_Float16)(n1w * SQRTL2E);
  *(f16x4*)(zh + (size_t)row * DIM + 4 * li) = h;

  __shared__ float sposL[32];
  if (li == 0)
    sposL[wid * 2 + half] = logf(expf(-0.5f * dp) + 1e-8f) + 1.0f;  // f'(g_pos)
  __syncthreads();
  if (threadIdx.x == 0) {
    float s = 0.0f;
#pragma unroll
    for (int k = 0; k < 32; ++k) s += sposL[k];
    sposB[blockIdx.x] = s;
  }
}

// ---------------------------------------------------------------------------
// Stage one 128-row B panel (32 KiB) into LDS via global_load_lds width=16.
// LDS dest linear; global source pre-swizzled (granule col ^= row&15);
// read side applies the same XOR (involution; rounds 3-16 verified,
// 0 bank conflicts). 4 VMEM instructions per wave.
// ---------------------------------------------------------------------------
__device__ __forceinline__ void stageB(const _Float16* __restrict__ zh,
                                       _Float16* buf, int ct, int wid,
                                       int lane) {
  const _Float16* base = zh + ((size_t)ct << 7) * DIM;
#pragma unroll
  for (int it = 0; it < 4; ++it) {
    const int P = it * 8 + wid;          // wave-uniform 4-row group 0..31
    const int R = P * 4 + (lane >> 4);   // row 0..127
    const int cs = (lane & 15) ^ (R & 15);
    __builtin_amdgcn_global_load_lds(AS1(base + (size_t)R * DIM + cs * 8),
                                     AS3(buf + P * 512), 16, 0, 0);
  }
}

// ---------------------------------------------------------------------------
// Kernel 2: champion pairwise (R9/R16 structure) + fused-constant epilogue.
// 512 blocks x 512 threads (8 waves, 4M x 2N); wave = 32 A-rows in regs x
// 64 B-cols from LDS (2 ds_read_b128 -> 2 MFMA per K-step). B double-
// buffered (2 x 32 KiB); next tile staged before compute with counted
// s_waitcnt vmcnt(4) (T4). NEW: acc initialized to -L2E (MFMA D = A*B + C)
// and zh pre-scaled by sqrt(L2E) -> acc_final = L2E*dot - L2E and the
// epilogue is just gsum += exp2(acc[r]): 2 ops/pair (was 3), deleting 34M
// VALU fmas from the largest pipe. Two separate tsum accumulators for ILP /
// packed adds. Diagonal masked; off-diag tiles x2. Block c owns tiles
// [4c+nx, +len) of the flat triangular list (len=5 when c%16==0).
// XCD swizzle (bid&7)*64+bid>>3 (bijective, 260 tiles/XCD). No atomics.
// ---------------------------------------------------------------------------
__global__ __launch_bounds__(512, 4) void fmicl_pairwise(
    const _Float16* __restrict__ zh, float* __restrict__ pairP) {
  __shared__ _Float16 B0[128 * DIM];  // 32 KiB
  __shared__ _Float16 B1[128 * DIM];  // 32 KiB
  __shared__ float wsum[8];

  const int tid = threadIdx.x;
  const int lane = tid & 63;
  const int wid = tid >> 6;
  const int l31 = lane & 31;
  const int lhi = lane >> 5;
  const int m = wid >> 1;  // 0..3: 32-row block of the band
  const int n = wid & 1;   // 0..1: 64-col half of the tile

  // XCD-chunked swizzle (512 = 8*64, bijective; 260 tiles per XCD)
  const int c = (blockIdx.x & 7) * 64 + (blockIdx.x >> 3);
  const int nx = (c + 15) >> 4;  // len-5 chunks before c
  const int base = 4 * c + nx;
  const int len = 4 + ((c & 15) == 0 ? 1 : 0);

  // ---- decode base -> (rt, ct); C(r) = r*NT - r(r-1)/2 ----
  int rt = (int)(64.5f - sqrtf(64.5f * 64.5f - 2.0f * (float)base));
  if (rt < 0) rt = 0;
  while (rt > 0 && (rt * NT - (rt * (rt - 1)) / 2) > base) --rt;
  while (((rt + 1) * NT - ((rt + 1) * rt) / 2) <= base) ++rt;
  int ctt = rt + (base - (rt * NT - (rt * (rt - 1)) / 2));
  int rtt = rt;

  stageB(zh, B0, ctt, wid, lane);  // prologue stage of tile 0

  uint4 areg[8];
  int cur_rt = -1;
  float gsum = 0.0f;

#pragma unroll 1
  for (int t = 0; t < len; ++t) {
    // ---- A-regs: reload only on band crossing ----
    if (rtt != cur_rt) {
      cur_rt = rtt;
      const uint4* ar =
          (const uint4*)(zh + (size_t)((rtt << 7) + m * 32 + l31) * DIM);
#pragma unroll
      for (int ks = 0; ks < 8; ++ks) areg[ks] = ar[2 * ks + lhi];
    }
    // ---- next tile coords; issue its stage before computing this one ----
    int nrt = rtt, nct = ctt + 1;
    if (nct == NT) { ++nrt; nct = nrt; }
    if (t + 1 < len) {
      stageB(zh, (t & 1) ? B0 : B1, nct, wid, lane);
      // all but the newest 4 loads (= next tile's stage) complete: current
      // B-panel + any A-reload are in. Next stage flies across the barrier.
      asm volatile("s_waitcnt vmcnt(4)" ::: "memory");
    } else {
      asm volatile("s_waitcnt vmcnt(0)" ::: "memory");
    }
    __builtin_amdgcn_s_barrier();
    __builtin_amdgcn_sched_barrier(0);

    // ---- compute: 8 K-steps, 2 B-reads -> 2 MFMA (A from registers).
    //      acc starts at -L2E: final acc[r] = L2E*dot - L2E (C-input fusion)
    const uint4* B4 = (const uint4*)((t & 1) ? B1 : B0);
    const int rb0 = n * 64 + l31;
    const int rb1 = n * 64 + 32 + l31;
    f32x16 acc0, acc1;
#pragma unroll
    for (int r = 0; r < 16; ++r) {
      acc0[r] = -L2E;
      acc1[r] = -L2E;
    }
#pragma unroll
    for (int ks = 0; ks < 8; ++ks) {
      const int kg = 2 * ks + lhi;
      const uint4 vb0 = B4[rb0 * 16 + (kg ^ (rb0 & 15))];
      const uint4 vb1 = B4[rb1 * 16 + (kg ^ (rb1 & 15))];
      const f16x8 af = __builtin_bit_cast(f16x8, areg[ks]);
      acc0 = __builtin_amdgcn_mfma_f32_32x32x16_f16(
          af, __builtin_bit_cast(f16x8, vb0), acc0, 0, 0, 0);
      acc1 = __builtin_amdgcn_mfma_f32_32x32x16_f16(
          af, __builtin_bit_cast(f16x8, vb1), acc1, 0, 0, 0);
    }

    // ---- epilogue: g = exp2(acc[r]) == exp(dot-1) == exp(-d2/2) ----
    // C/D layout (32x32): col=lane&31, row=(reg&3)+8*(reg>>2)+4*(lane>>5)
    float tsum0 = 0.0f, tsum1 = 0.0f;
    const bool dsub0 = (rtt == ctt) && (m == 2 * n);      // chain-0 diag
    const bool dsub1 = (rtt == ctt) && (m == 2 * n + 1);  // chain-1 diag
    if (dsub0 || dsub1) {
#pragma unroll
      for (int r = 0; r < 16; ++r) {
        const float e0 = __builtin_amdgcn_exp2f(acc0[r]);
        const float e1 = __builtin_amdgcn_exp2f(acc1[r]);
        const int mloc = (r & 3) + 4 * lhi + 8 * (r >> 2);
        tsum0 += (dsub0 && mloc == l31) ? 0.0f : e0;
        tsum1 += (dsub1 && mloc == l31) ? 0.0f : e1;
      }
    } else {
#pragma unroll
      for (int r = 0; r < 16; ++r) {
        tsum0 += __builtin_amdgcn_exp2f(acc0[r]);
        tsum1 += __builtin_amdgcn_exp2f(acc1[r]);
      }
    }
    const float tsum = tsum0 + tsum1;
    gsum += (rtt == ctt) ? tsum : (tsum + tsum);  // off-diag mirrored x2

    __builtin_amdgcn_s_barrier();  // buf reads done before its re-stage
    rtt = nrt;
    ctt = nct;
  }

  // ---- per-block reduction -> pairP[c] ----
#pragma unroll
  for (int off = 32; off; off >>= 1) gsum += __shfl_xor(gsum, off);
  if (lane == 0) wsum[wid] = gsum;
  __syncthreads();
  if (tid == 0) {
    float s = 0.0f;
#pragma unroll
    for (int q = 0; q < 8; ++q) s += wsum[q];
    pairP[c] = s;
  }
}

// ---------------------------------------------------------------------------
// Kernel 3: single-block fused reduce + assemble scalar (deterministic
// fixed-order tree). star_neg = g + EPS exactly, so
// star_mean = negSum/(N(N-1)) + EPS.
// ---------------------------------------------------------------------------
__global__ void fmicl_reduce(const float* __restrict__ pairP,
                             const float* __restrict__ sposB,
                             float* __restrict__ out) {
  const int t = threadIdx.x;  // 1024 threads = 16 waves
  double nsum = (t < NBLK) ? (double)pairP[t] : 0.0;
  double psum = (t < 256) ? (double)sposB[t] : 0.0;
#pragma unroll
  for (int off = 32; off; off >>= 1) {
    nsum += __shfl_xor(nsum, off);
    psum += __shfl_xor(psum, off);
  }
  __shared__ double ls[2][16];
  const int lane = t & 63;
  const int wid = t >> 6;
  if (lane == 0) {
    ls[0][wid] = nsum;
    ls[1][wid] = psum;
  }
  __syncthreads();
  if (t == 0) {
    double nn = 0.0, pp = 0.0;
#pragma unroll
    for (int q = 0; q < 16; ++q) {
      nn += ls[0][q];
      pp += ls[1][q];
    }
    const double pos_mean = pp / (double)NROWS;
    const double star_mean = nn / ((double)NROWS * (double)(NROWS - 1)) + 1e-8;
    out[0] = (float)(-pos_mean + 1.5 * star_mean);
  }
}

extern "C" void kernel_launch(void* const* d_in, const int* in_sizes, int n_in,
                              void* d_out, int out_size, void* d_ws,
                              size_t ws_size, hipStream_t stream) {
  const float* z1 = (const float*)d_in[0];
  const float* z2 = (const float*)d_in[1];
  float* out = (float*)d_out;
  char* ws = (char*)d_ws;

  // ws layout (every slot rewritten every call; no memset needed):
  //   [0)     pairP float[512]    (2048 B, pad to 4096)
  //   [4096)  sposB float[256]    (1024 B)
  //   [6144)  zh    f16[8192*128] (2 MiB, 16B-aligned)
  float* pairP = (float*)(ws + 0);
  float* sposB = (float*)(ws + 4096);
  _Float16* zh = (_Float16*)(ws + 6144);

  fmicl_normalize<<<256, 1024, 0, stream>>>(z1, z2, zh, sposB);
  fmicl_pairwise<<<NBLK, 512, 0, stream>>>(zh, pairP);
  fmicl_reduce<<<1, 1024, 0, stream>>>(pairP, sposB, out);
}